// Round 5
// baseline (283.603 us; speedup 1.0000x reference)
//
#include <hip/hip_runtime.h>
#include <hip/hip_bf16.h>

typedef __bf16 bf16_t;
typedef bf16_t bf16x8 __attribute__((ext_vector_type(8)));
typedef bf16_t bf16x4 __attribute__((ext_vector_type(4)));
typedef float f32x4 __attribute__((ext_vector_type(4)));

// H=8 D=31 T=4 P=50 C=248 O=744 B=512, DT=124, SCALE=31^-0.5
constexpr float SCALE = 0.17960530202677491f;

__device__ __forceinline__ f32x4 mfma16(bf16x8 a, bf16x8 b, f32x4 c) {
    return __builtin_amdgcn_mfma_f32_16x16x32_bf16(a, b, c, 0, 0, 0);
}

__device__ __forceinline__ void wave_lds_fence() {
    asm volatile("s_waitcnt lgkmcnt(0)" ::: "memory");
}

__device__ __forceinline__ void opaque(bf16x8& v) {
    asm volatile("" : "+v"(v));   // pin value in VGPRs; block rematerialization
}

// ---------------------------------------------------------------------------
// prep: W -> per-(head,mtile,kstep) fragment-contiguous, rel -> frag blocks
// (rt 0..6, rows 99..111 zero), bias -> bp[h][96].
// ---------------------------------------------------------------------------
__global__ void prep_kernel(const float* __restrict__ w, const float* __restrict__ b_qkv,
                            const float* __restrict__ rel,
                            bf16_t* __restrict__ Wf, bf16_t* __restrict__ relf,
                            float* __restrict__ bp)
{
    int i = blockIdx.x * 256 + threadIdx.x;
    if (i < 196608) {                    // Wf
        int e = i & 7, lane = (i >> 3) & 63;
        int f = i >> 9;                  // (h*6+m)*8+ks
        int ks = f & 7, g = f >> 3;
        int h = g / 6, m = g - h * 6;
        int r15 = lane & 15, g4 = lane >> 4;
        int s = m >> 1, d = ((m & 1) << 4) + r15;
        int c = ks * 32 + g4 * 8 + e;
        float v = 0.f;
        if (d < 31 && c < 248) v = w[(long)(s * 248 + h * 31 + d) * 248 + c];
        Wf[i] = (bf16_t)v;
        return;
    }
    i -= 196608;
    if (i < 14336) {                     // relf: rt 0..6
        int e = i & 7, lane = (i >> 3) & 63;
        int f = i >> 9;                  // rt*4+ks
        int ks = f & 3, rt = f >> 2;
        int r = rt * 16 + (lane & 15);
        int dt = ks * 32 + (lane >> 4) * 8 + e;
        float v = 0.f;
        if (r < 99 && dt < 124) v = rel[r * 124 + dt];
        relf[i] = (bf16_t)v;
        return;
    }
    i -= 14336;
    if (i < 768) {                       // bp[h][96]
        int h = i / 96, row = i - h * 96;
        int s = row >> 5, d = row & 31;
        bp[i] = (d < 31) ? b_qkv[s * 248 + h * 31 + d] : 0.f;
    }
}

// ---------------------------------------------------------------------------
// Fused kernel: one block per batch b. 256 threads = 4 waves, ~71 KB LDS
// -> 2 blocks/CU. amdgpu_waves_per_eu(2,2): allocator budget 256 VGPR.
// ---------------------------------------------------------------------------
__global__ void __launch_bounds__(256)
__attribute__((amdgpu_waves_per_eu(2, 2)))
fused_kernel(const float* __restrict__ x, const bf16_t* __restrict__ Wf,
             const bf16_t* __restrict__ relf, const float* __restrict__ bp,
             float* __restrict__ out)
{
    // swizzled tiles: row-chunk 16B, hash = row&7 (QH/KH/AS), (row>>2)&7 (VT)
    __shared__ __align__(16) bf16_t QH[64][128];   // q[p][dt]
    __shared__ __align__(16) bf16_t KH[64][128];   // k[p'][dt]
    __shared__ __align__(16) bf16_t AS[64][64];    // attn[p][p'] bf16
    __shared__ __align__(16) bf16_t VT[128][64];   // v[i][p']
    __shared__ float LS[50][68];                   // logits[p][p'] f32

    const int b    = blockIdx.x;
    const int tid  = threadIdx.x;
    const int lane = tid & 63;
    const int w    = tid >> 6;           // 0..3
    const int r15  = lane & 15, g4 = lane >> 4;

    // ================= phase 0: zero pads =================
    {
        *(f32x4*)((char*)&VT[0][0] + tid * 64)      = f32x4{0.f, 0.f, 0.f, 0.f};
        *(f32x4*)((char*)&VT[0][0] + tid * 64 + 16) = f32x4{0.f, 0.f, 0.f, 0.f};
        *(f32x4*)((char*)&VT[0][0] + tid * 64 + 32) = f32x4{0.f, 0.f, 0.f, 0.f};
        *(f32x4*)((char*)&VT[0][0] + tid * 64 + 48) = f32x4{0.f, 0.f, 0.f, 0.f};
        if (tid < 128) {
            int row = tid & 63;
            char* base = (tid < 64) ? (char*)&QH[0][0] : (char*)&KH[0][0];
            int chunk = 15 ^ (row & 7);
            *(long*)(base + row * 256 + chunk * 16 + 8) = 0L;
        }
    }

    // ================= phase 1: A fragments straight from global x ==========
    const float* xb = x + (long)b * 49600;
    bf16x8 Areg[4][8];
#pragma unroll
    for (int ui = 0; ui < 4; ++ui) {
        int n = w * 64 + ui * 16 + r15;
        const float* xn = xb + n;
        bool nok = (n < 200);
#pragma unroll
        for (int ks = 0; ks < 8; ++ks) {
            bf16x8 fr;
#pragma unroll
            for (int e = 0; e < 8; ++e) {
                int c = ks * 32 + g4 * 8 + e;
                float v = (nok && c < 248) ? xn[(long)c * 200] : 0.f;
                fr[e] = (bf16_t)v;
            }
            Areg[ui][ks] = fr;
        }
    }
#pragma unroll
    for (int ui = 0; ui < 4; ++ui)
#pragma unroll
        for (int ks = 0; ks < 8; ++ks)
            opaque(Areg[ui][ks]);
    __syncthreads();   // pads + Areg complete before head loop

    // ================= head loop =================
    for (int h = 0; h < 8; ++h) {
        // ---- qkv GEMM: all 6 m-tiles; Wf frags loaded per tile (L2-hot) ----
        const bf16_t* wf = Wf + ((long)(h * 48) << 9) + lane * 8;
#pragma unroll
        for (int m = 0; m < 6; ++m) {
            bf16x8 Bc[8];
#pragma unroll
            for (int ks = 0; ks < 8; ++ks)
                Bc[ks] = *(const bf16x8*)(wf + ((m * 8 + ks) << 9));
            f32x4 acc[4];
#pragma unroll
            for (int ui = 0; ui < 4; ++ui) acc[ui] = f32x4{0.f, 0.f, 0.f, 0.f};
#pragma unroll
            for (int ks = 0; ks < 8; ++ks)
#pragma unroll
                for (int ui = 0; ui < 4; ++ui)
                    acc[ui] = mfma16(Areg[ui][ks], Bc[ks], acc[ui]);

            int s = m >> 1;
            int d = ((m & 1) << 4) + r15;          // 0..31
            float bias = bp[h * 96 + m * 16 + r15];
            if (d < 31) {
#pragma unroll
                for (int ui = 0; ui < 4; ++ui) {
                    int p = (w * 4 + ui) * 4 + g4;
                    if (p >= 50) continue;
                    float a0 = acc[ui][0] + bias, a1 = acc[ui][1] + bias;
                    float a2 = acc[ui][2] + bias, a3 = acc[ui][3] + bias;
                    if (s < 2) {
                        bf16x4 pk = {(bf16_t)a0, (bf16_t)a1, (bf16_t)a2, (bf16_t)a3};
                        char* base = (s == 0) ? (char*)&QH[0][0] : (char*)&KH[0][0];
                        int chunk = (d >> 1) ^ (p & 7);
                        *(bf16x4*)(base + p * 256 + chunk * 16 + ((d & 1) << 3)) = pk;
                    } else {
                        int chunk = ((p >> 3) ^ (d & 7)) << 4;
                        char* vbase = (char*)&VT[0][0] + (d * 4) * 128 + chunk + (p & 7) * 2;
                        *(bf16_t*)(vbase)       = (bf16_t)a0;
                        *(bf16_t*)(vbase + 128) = (bf16_t)a1;
                        *(bf16_t*)(vbase + 256) = (bf16_t)a2;
                        *(bf16_t*)(vbase + 384) = (bf16_t)a3;
                    }
                }
            }
        }
        __syncthreads();   // qkv tiles ready for all waves

        // ---- scores + softmax (wave-private q-rows w*16..w*16+15) ----
        bf16x8 Afr[4];
        {
            int p = w * 16 + r15;
            int hp = p & 7;
#pragma unroll
            for (int ks = 0; ks < 4; ++ks)
                Afr[ks] = *(const bf16x8*)((char*)&QH[0][0] + p * 256 + ((((ks << 2) | g4) ^ hp) << 4));
        }
        // dots: all 4 key tiles -> LS
#pragma unroll
        for (int ct = 0; ct < 4; ++ct) {
            int c = ct * 16 + r15;
            int hc = c & 7;
            f32x4 s = f32x4{0.f, 0.f, 0.f, 0.f};
#pragma unroll
            for (int ks = 0; ks < 4; ++ks) {
                bf16x8 Bf = *(const bf16x8*)((char*)&KH[0][0] + c * 256 + ((((ks << 2) | g4) ^ hc) << 4));
                s = mfma16(Afr[ks], Bf, s);
            }
            if (c < 50) {
#pragma unroll
                for (int j = 0; j < 4; ++j) {
                    int qrow = w * 16 + g4 * 4 + j;
                    if (qrow < 50) LS[qrow][c] = s[j];
                }
            }
        }
        wave_lds_fence();
        // rel bias: rt 0..6; scatter-add jj = r + qrow - 49
        {
            const bf16_t* rf = relf + lane * 8;
            for (int rt = 0; rt < 7; ++rt) {
                f32x4 s = f32x4{0.f, 0.f, 0.f, 0.f};
#pragma unroll
                for (int ks = 0; ks < 4; ++ks) {
                    bf16x8 R = *(const bf16x8*)(rf + ((rt * 4 + ks) << 9));
                    s = mfma16(Afr[ks], R, s);
                }
                int r = rt * 16 + r15;
#pragma unroll
                for (int j = 0; j < 4; ++j) {
                    int qrow = w * 16 + g4 * 4 + j;
                    int jj = r + qrow - 49;
                    if (qrow < 50 && jj >= 0 && jj < 50) LS[qrow][jj] += s[j];
                }
            }
        }
        wave_lds_fence();
        // softmax: 4 lanes per row
        {
            int row = w * 16 + (lane >> 2);
            int quad = lane & 3;
            if (row < 50) {
                float mx = -1e30f;
                for (int jj = quad; jj < 50; jj += 4) mx = fmaxf(mx, LS[row][jj]);
                mx = fmaxf(mx, __shfl_xor(mx, 1));
                mx = fmaxf(mx, __shfl_xor(mx, 2));
                float sum = 0.f;
                for (int jj = quad; jj < 50; jj += 4) {
                    float e = __expf((LS[row][jj] - mx) * SCALE);
                    LS[row][jj] = e;
                    sum += e;
                }
                sum += __shfl_xor(sum, 1);
                sum += __shfl_xor(sum, 2);
                float rs = 1.f / sum;
                int hrow = row & 7;
                for (int jj = quad; jj < 64; jj += 4) {
                    float v = (jj < 50) ? LS[row][jj] * rs : 0.f;
                    *(bf16_t*)((char*)&AS[0][0] + row * 128 + (((jj >> 3) ^ hrow) << 4) + (jj & 7) * 2) = (bf16_t)v;
                }
            }
        }
        __syncthreads();   // AS/VT ready for all waves

        // ---- PV: wave w owns i-tiles {2w, 2w+1}; all 4 p-tiles ----
#pragma unroll
        for (int ii = 0; ii < 2; ++ii) {
            int it = w * 2 + ii;
            int irow = it * 16 + r15;
            int hv = (irow >> 2) & 7;
            bf16x8 Av[2];
#pragma unroll
            for (int ks = 0; ks < 2; ++ks)
                Av[ks] = *(const bf16x8*)((char*)&VT[0][0] + irow * 128 + ((((ks << 2) | g4) ^ hv) << 4));
            int dd = it * 4 + g4;
#pragma unroll
            for (int pt = 0; pt < 4; ++pt) {
                int prow = pt * 16 + r15;
                int hp2 = prow & 7;
                f32x4 po = f32x4{0.f, 0.f, 0.f, 0.f};
#pragma unroll
                for (int ks = 0; ks < 2; ++ks) {
                    bf16x8 Bs = *(const bf16x8*)((char*)&AS[0][0] + prow * 128 + ((((ks << 2) | g4) ^ hp2) << 4));
                    po = mfma16(Av[ks], Bs, po);
                }
                if (dd < 31 && prow < 50)
                    *(f32x4*)(out + ((long)b * 248 + h * 31 + dd) * 200 + prow * 4) = po;
            }
        }
        __syncthreads();   // protect QH/KH/VT/AS/LS rewrite by next head
    }
}

// ---------------------------------------------------------------------------
extern "C" void kernel_launch(void* const* d_in, const int* in_sizes, int n_in,
                              void* d_out, int out_size, void* d_ws, size_t ws_size,
                              hipStream_t stream)
{
    const float* x   = (const float*)d_in[0];
    const float* wq  = (const float*)d_in[1];
    const float* bq  = (const float*)d_in[2];
    const float* rel = (const float*)d_in[3];
    float* out = (float*)d_out;

    char* ws = (char*)d_ws;
    bf16_t* Wf   = (bf16_t*)ws;                    // 196,608 elems = 393,216 B
    bf16_t* relf = (bf16_t*)(ws + 393216);         // 14,336 elems  = 28,672 B
    float*  bp   = (float*)(ws + 421888);          // 768 f32       = 3,072 B

    const int B = in_sizes[0] / 49600;

    prep_kernel<<<dim3(828), dim3(256), 0, stream>>>(wq, bq, rel, Wf, relf, bp);
    fused_kernel<<<dim3(B), dim3(256), 0, stream>>>(x, Wf, relf, bp, out);
}

// Round 6
// 205.352 us; speedup vs baseline: 1.3811x; 1.3811x over previous
//
#include <hip/hip_runtime.h>
#include <hip/hip_bf16.h>

typedef __bf16 bf16_t;
typedef bf16_t bf16x8 __attribute__((ext_vector_type(8)));
typedef bf16_t bf16x4 __attribute__((ext_vector_type(4)));
typedef float f32x4 __attribute__((ext_vector_type(4)));

// H=8 D=31 T=4 P=50 C=248 O=744 B=512, DT=124, SCALE=31^-0.5
constexpr float SCALE = 0.17960530202677491f;

__device__ __forceinline__ f32x4 mfma16(bf16x8 a, bf16x8 b, f32x4 c) {
    return __builtin_amdgcn_mfma_f32_16x16x32_bf16(a, b, c, 0, 0, 0);
}

__device__ __forceinline__ void opaque(bf16x8& v) {
    asm volatile("" : "+v"(v));   // pin in VGPRs; block rematerialization
}

// ---------------------------------------------------------------------------
// prep: W -> per-(head,mtile,kstep) fragment-contiguous, rel -> frag blocks
// (rt 0..6, rows 99..111 zero), bias -> bp[h][96].
// ---------------------------------------------------------------------------
__global__ void prep_kernel(const float* __restrict__ w, const float* __restrict__ b_qkv,
                            const float* __restrict__ rel,
                            bf16_t* __restrict__ Wf, bf16_t* __restrict__ relf,
                            float* __restrict__ bp)
{
    int i = blockIdx.x * 256 + threadIdx.x;
    if (i < 196608) {                    // Wf
        int e = i & 7, lane = (i >> 3) & 63;
        int f = i >> 9;                  // (h*6+m)*8+ks
        int ks = f & 7, g = f >> 3;
        int h = g / 6, m = g - h * 6;
        int r15 = lane & 15, g4 = lane >> 4;
        int s = m >> 1, d = ((m & 1) << 4) + r15;
        int c = ks * 32 + g4 * 8 + e;
        float v = 0.f;
        if (d < 31 && c < 248) v = w[(long)(s * 248 + h * 31 + d) * 248 + c];
        Wf[i] = (bf16_t)v;
        return;
    }
    i -= 196608;
    if (i < 14336) {                     // relf: rt 0..6
        int e = i & 7, lane = (i >> 3) & 63;
        int f = i >> 9;                  // rt*4+ks
        int ks = f & 3, rt = f >> 2;
        int r = rt * 16 + (lane & 15);
        int dt = ks * 32 + (lane >> 4) * 8 + e;
        float v = 0.f;
        if (r < 99 && dt < 124) v = rel[r * 124 + dt];
        relf[i] = (bf16_t)v;
        return;
    }
    i -= 14336;
    if (i < 768) {                       // bp[h][96]
        int h = i / 96, row = i - h * 96;
        int s = row >> 5, d = row & 31;
        bp[i] = (d < 31) ? b_qkv[s * 248 + h * 31 + d] : 0.f;
    }
}

// ---------------------------------------------------------------------------
// Fused kernel: one block per batch b. 512 threads = 8 waves, ~71 KB LDS
// -> 2 blocks/CU, 16 waves/CU. Per-wave A-state 64 VGPR; total fits 128 cap.
// ---------------------------------------------------------------------------
__global__ void __launch_bounds__(512, 4)
fused_kernel(const float* __restrict__ x, const bf16_t* __restrict__ Wf,
             const bf16_t* __restrict__ relf, const float* __restrict__ bp,
             float* __restrict__ out)
{
    // swizzled tiles: 16B chunks, hash = row&7 (QH/KH/AS), (row>>2)&7 (VT)
    __shared__ __align__(16) bf16_t QH[64][128];   // q[p][dt]
    __shared__ __align__(16) bf16_t KH[64][128];   // k[p'][dt]
    __shared__ __align__(16) bf16_t AS[64][64];    // attn[p][p'] bf16
    __shared__ __align__(16) bf16_t VT[128][64];   // v[i][p']
    __shared__ float LS[50][68];                   // logits[p][p'] f32

    const int b    = blockIdx.x;
    const int tid  = threadIdx.x;
    const int lane = tid & 63;
    const int w    = tid >> 6;           // 0..7
    const int r15  = lane & 15, g4 = lane >> 4;

    // ================= phase 0: zero pads =================
    {
        // VT fully zero (cols p'=50..63, rows i=124..127 must stay 0)
        *(f32x4*)((char*)&VT[0][0] + tid * 32)      = f32x4{0.f, 0.f, 0.f, 0.f};
        *(f32x4*)((char*)&VT[0][0] + tid * 32 + 16) = f32x4{0.f, 0.f, 0.f, 0.f};
        // QH/KH dt-pad cols 124..127 (chunk 15^hash, upper 8B), rows 0..63
        if (tid < 128) {
            int row = tid & 63;
            char* base = (tid < 64) ? (char*)&QH[0][0] : (char*)&KH[0][0];
            int chunk = 15 ^ (row & 7);
            *(long*)(base + row * 256 + chunk * 16 + 8) = 0L;
        }
    }

    // ================= phase 1: A fragments straight from global x ==========
    // wave w owns n-tiles {w, w+8}; frag (ui,ks): n = (w+8ui)*16+r15,
    // c = ks*32+g4*8+e. Tiles 13..15 are dead (n>=208).
    const float* xb = x + (long)b * 49600;
    const int tile0 = w, tile1 = w + 8;
    const bool t1ok = (tile1 * 16 < 200);           // tiles 8..12 real
    bf16x8 Areg[2][8];
#pragma unroll
    for (int ui = 0; ui < 2; ++ui) {
        int n = (w + 8 * ui) * 16 + r15;
        const float* xn = xb + n;
        bool nok = (n < 200);
#pragma unroll
        for (int ks = 0; ks < 8; ++ks) {
            bf16x8 fr;
#pragma unroll
            for (int e = 0; e < 8; ++e) {
                int c = ks * 32 + g4 * 8 + e;
                float v = (nok && c < 248) ? xn[(long)c * 200] : 0.f;
                fr[e] = (bf16_t)v;
            }
            Areg[ui][ks] = fr;
        }
    }
#pragma unroll
    for (int ui = 0; ui < 2; ++ui)
#pragma unroll
        for (int ks = 0; ks < 8; ++ks)
            opaque(Areg[ui][ks]);
    __syncthreads();   // pads complete before head loop

    const int qt  = w >> 1, par = w & 1;   // scores roles
    // ================= head loop =================
    for (int h = 0; h < 8; ++h) {
        // ---- qkv GEMM: 6 m-tiles; B frags streamed in halves of 4 ----
        const bf16_t* wf = Wf + ((long)(h * 48) << 9) + lane * 8;
#pragma unroll
        for (int m = 0; m < 6; ++m) {
            f32x4 acc0 = f32x4{0.f, 0.f, 0.f, 0.f};
            f32x4 acc1 = f32x4{0.f, 0.f, 0.f, 0.f};
#pragma unroll
            for (int half = 0; half < 2; ++half) {
                bf16x8 Bc[4];
#pragma unroll
                for (int k4 = 0; k4 < 4; ++k4)
                    Bc[k4] = *(const bf16x8*)(wf + ((m * 8 + half * 4 + k4) << 9));
#pragma unroll
                for (int k4 = 0; k4 < 4; ++k4) {
                    int ks = half * 4 + k4;
                    acc0 = mfma16(Areg[0][ks], Bc[k4], acc0);
                    if (t1ok) acc1 = mfma16(Areg[1][ks], Bc[k4], acc1);
                }
            }
            int s = m >> 1;
            int d = ((m & 1) << 4) + r15;          // 0..31
            float bias = bp[h * 96 + m * 16 + r15];
            if (d < 31) {
#pragma unroll
                for (int ui = 0; ui < 2; ++ui) {
                    if (ui == 1 && !t1ok) continue;
                    f32x4 a = ui ? acc1 : acc0;
                    int p = (w + 8 * ui) * 4 + g4;
                    if (p >= 50) continue;
                    float a0 = a[0] + bias, a1 = a[1] + bias;
                    float a2 = a[2] + bias, a3 = a[3] + bias;
                    if (s < 2) {
                        bf16x4 pk = {(bf16_t)a0, (bf16_t)a1, (bf16_t)a2, (bf16_t)a3};
                        char* base = (s == 0) ? (char*)&QH[0][0] : (char*)&KH[0][0];
                        int chunk = (d >> 1) ^ (p & 7);
                        *(bf16x4*)(base + p * 256 + chunk * 16 + ((d & 1) << 3)) = pk;
                    } else {
                        int chunk = ((p >> 3) ^ (d & 7)) << 4;
                        char* vbase = (char*)&VT[0][0] + (d * 4) * 128 + chunk + (p & 7) * 2;
                        *(bf16_t*)(vbase)       = (bf16_t)a0;
                        *(bf16_t*)(vbase + 128) = (bf16_t)a1;
                        *(bf16_t*)(vbase + 256) = (bf16_t)a2;
                        *(bf16_t*)(vbase + 384) = (bf16_t)a3;
                    }
                }
            }
        }
        __syncthreads();   // qkv tiles ready

        // ---- scores: wave (qt, par). dots: ct = par*2 + {0,1} ----
        bf16x8 Afr[4];
        {
            int p = qt * 16 + r15;
            int hp = p & 7;
#pragma unroll
            for (int ks = 0; ks < 4; ++ks)
                Afr[ks] = *(const bf16x8*)((char*)&QH[0][0] + p * 256 + ((((ks << 2) | g4) ^ hp) << 4));
        }
#pragma unroll
        for (int i = 0; i < 2; ++i) {
            int ct = par * 2 + i;
            int c = ct * 16 + r15;
            int hc = c & 7;
            f32x4 s = f32x4{0.f, 0.f, 0.f, 0.f};
#pragma unroll
            for (int ks = 0; ks < 4; ++ks) {
                bf16x8 Bf = *(const bf16x8*)((char*)&KH[0][0] + c * 256 + ((((ks << 2) | g4) ^ hc) << 4));
                s = mfma16(Afr[ks], Bf, s);
            }
            if (c < 50) {
#pragma unroll
                for (int j = 0; j < 4; ++j) {
                    int qrow = qt * 16 + g4 * 4 + j;
                    if (qrow < 50) LS[qrow][c] = s[j];
                }
            }
        }
        __syncthreads();   // all dots of each q-tile visible

        // ---- rel bias: rt = par, par+2, ... (each (qrow,jj) hit by one rt) ----
        {
            const bf16_t* rf = relf + lane * 8;
            for (int rt = par; rt < 7; rt += 2) {
                f32x4 s = f32x4{0.f, 0.f, 0.f, 0.f};
#pragma unroll
                for (int ks = 0; ks < 4; ++ks) {
                    bf16x8 R = *(const bf16x8*)(rf + ((rt * 4 + ks) << 9));
                    s = mfma16(Afr[ks], R, s);
                }
                int r = rt * 16 + r15;
#pragma unroll
                for (int j = 0; j < 4; ++j) {
                    int qrow = qt * 16 + g4 * 4 + j;
                    int jj = r + qrow - 49;
                    if (qrow < 50 && jj >= 0 && jj < 50) LS[qrow][jj] += s[j];
                }
            }
        }
        __syncthreads();   // all rel adds visible

        // ---- softmax: row = tid>>3 (0..63), 8 lanes/row ----
        {
            int row = tid >> 3, sub = tid & 7;
            int hrow = row & 7;
            if (row < 50) {
                float mx = -1e30f;
                for (int jj = sub; jj < 50; jj += 8) mx = fmaxf(mx, LS[row][jj]);
                mx = fmaxf(mx, __shfl_xor(mx, 1));
                mx = fmaxf(mx, __shfl_xor(mx, 2));
                mx = fmaxf(mx, __shfl_xor(mx, 4));
                float sum = 0.f;
                for (int jj = sub; jj < 50; jj += 8) {
                    float e = __expf((LS[row][jj] - mx) * SCALE);
                    LS[row][jj] = e;
                    sum += e;
                }
                sum += __shfl_xor(sum, 1);
                sum += __shfl_xor(sum, 2);
                sum += __shfl_xor(sum, 4);
                float rs = 1.f / sum;
                for (int jj = sub; jj < 64; jj += 8) {
                    float v = (jj < 50) ? LS[row][jj] * rs : 0.f;
                    *(bf16_t*)((char*)&AS[0][0] + row * 128 + (((jj >> 3) ^ hrow) << 4) + (jj & 7) * 2) = (bf16_t)v;
                }
            } else {
                for (int jj = sub; jj < 64; jj += 8)
                    *(bf16_t*)((char*)&AS[0][0] + row * 128 + (((jj >> 3) ^ hrow) << 4) + (jj & 7) * 2) = (bf16_t)0.f;
            }
        }
        __syncthreads();   // AS ready

        // ---- PV: wave w owns i-tile w; all 4 p-tiles ----
        {
            int irow = w * 16 + r15;
            int hv = (irow >> 2) & 7;
            bf16x8 Av[2];
#pragma unroll
            for (int ks = 0; ks < 2; ++ks)
                Av[ks] = *(const bf16x8*)((char*)&VT[0][0] + irow * 128 + ((((ks << 2) | g4) ^ hv) << 4));
            int dd = w * 4 + g4;
#pragma unroll
            for (int pt = 0; pt < 4; ++pt) {
                int prow = pt * 16 + r15;
                int hp2 = prow & 7;
                f32x4 po = f32x4{0.f, 0.f, 0.f, 0.f};
#pragma unroll
                for (int ks = 0; ks < 2; ++ks) {
                    bf16x8 Bs = *(const bf16x8*)((char*)&AS[0][0] + prow * 128 + ((((ks << 2) | g4) ^ hp2) << 4));
                    po = mfma16(Av[ks], Bs, po);
                }
                if (dd < 31 && prow < 50)
                    *(f32x4*)(out + ((long)b * 248 + h * 31 + dd) * 200 + prow * 4) = po;
            }
        }
        __syncthreads();   // protect LDS rewrite by next head
    }
}

// ---------------------------------------------------------------------------
extern "C" void kernel_launch(void* const* d_in, const int* in_sizes, int n_in,
                              void* d_out, int out_size, void* d_ws, size_t ws_size,
                              hipStream_t stream)
{
    const float* x   = (const float*)d_in[0];
    const float* wq  = (const float*)d_in[1];
    const float* bq  = (const float*)d_in[2];
    const float* rel = (const float*)d_in[3];
    float* out = (float*)d_out;

    char* ws = (char*)d_ws;
    bf16_t* Wf   = (bf16_t*)ws;                    // 196,608 elems = 393,216 B
    bf16_t* relf = (bf16_t*)(ws + 393216);         // 14,336 elems  = 28,672 B
    float*  bp   = (float*)(ws + 421888);          // 768 f32       = 3,072 B

    const int B = in_sizes[0] / 49600;

    prep_kernel<<<dim3(828), dim3(256), 0, stream>>>(wq, bq, rel, Wf, relf, bp);
    fused_kernel<<<dim3(B), dim3(512), 0, stream>>>(x, Wf, relf, bp, out);
}